// Round 2
// baseline (740.572 us; speedup 1.0000x reference)
//
#include <hip/hip_runtime.h>
#include <hip/hip_bf16.h>
#include <float.h>

#define N_NODES 30000
#define IN_CH   256
#define HID     128
#define HEADS   4
#define OUT_CH  256
#define N_EDGES 480000
#define TOT_E   (N_EDGES + N_NODES)

typedef unsigned short u16;   // bf16 bits

__device__ inline float bf2f(u16 u) {
    union { unsigned int i; float f; } v; v.i = ((unsigned int)u) << 16; return v.f;
}
__device__ inline u16 f2bf(float f) {
    union { float f; unsigned int i; } u; u.f = f;
    unsigned int r = u.i + 0x7FFF + ((u.i >> 16) & 1);
    return (u16)(r >> 16);
}

__device__ inline void load4(const float* p, float* o) {
    float4 v = *(const float4*)p; o[0]=v.x; o[1]=v.y; o[2]=v.z; o[3]=v.w;
}
__device__ inline void store4f(float* p, float a, float b, float c, float d) {
    *(float4*)p = make_float4(a,b,c,d);
}
__device__ inline void store4b(u16* p, float a, float b, float c, float d) {
    ushort4 o; o.x=f2bf(a); o.y=f2bf(b); o.z=f2bf(c); o.w=f2bf(d);
    *(ushort4*)p = o;
}

// ---------- dtype detection: bf16 exponent field vs fp32 mantissa bits -----
// word bits [14:7]: bf16 buffer -> exponent of element 0, concentrated
// ~[100,140] for N(0,1) data; fp32 buffer -> uniform mantissa bits (~16% hit).
__global__ void detect_k(const unsigned int* __restrict__ w, int* __restrict__ flag) {
    __shared__ int votes;
    if (threadIdx.x == 0) votes = 0;
    __syncthreads();
    int v = 0;
    for (int i = threadIdx.x; i < 2048; i += 256) {
        unsigned int e = (w[i] >> 7) & 0xFFu;
        if (e >= 100u && e <= 140u) v++;
    }
    atomicAdd(&votes, v);
    __syncthreads();
    if (threadIdx.x == 0) *flag = (votes > 1024) ? 1 : 0;
}

// materialize an input as fp32 regardless of its on-disk dtype
__global__ void convert_k(const void* __restrict__ in, float* __restrict__ out,
                          int n, const int* __restrict__ flag) {
    int i = blockIdx.x * blockDim.x + threadIdx.x;
    if (i >= n) return;
    if (*flag) out[i] = bf2f(((const u16*)in)[i]);
    else       out[i] = ((const float*)in)[i];
}

// ---------------- GEMM: C[M,N] = A[M,K] @ B[K,N], fp32 --------------------
__global__ __launch_bounds__(256) void gemm_k(const float* __restrict__ A,
                                              const float* __restrict__ B,
                                              float* __restrict__ C,
                                              int M, int N, int K)
{
    const int BK = 16;
    __shared__ float As[16][68];
    __shared__ float Bs[16][68];
    int tid = threadIdx.x;
    int tx = tid & 15, ty = tid >> 4;
    int row0 = blockIdx.y * 64;
    int col0 = blockIdx.x * 64;
    float acc[4][4] = {};
    int a_r = tid >> 2;
    int a_k = (tid & 3) << 2;
    int b_r = tid >> 4;
    int b_c = (tid & 15) << 2;

    for (int k0 = 0; k0 < K; k0 += BK) {
        float av[4] = {0.f,0.f,0.f,0.f};
        int ar = row0 + a_r;
        if (ar < M) load4(A + (size_t)ar * K + k0 + a_k, av);
        As[a_k+0][a_r]=av[0]; As[a_k+1][a_r]=av[1];
        As[a_k+2][a_r]=av[2]; As[a_k+3][a_r]=av[3];
        float bv[4];
        load4(B + (size_t)(k0 + b_r) * N + col0 + b_c, bv);
        *(float4*)&Bs[b_r][b_c] = make_float4(bv[0],bv[1],bv[2],bv[3]);
        __syncthreads();
#pragma unroll
        for (int k = 0; k < BK; ++k) {
            float4 a4 = *(float4*)&As[k][ty<<2];
            float4 b4 = *(float4*)&Bs[k][tx<<2];
            float a[4] = {a4.x,a4.y,a4.z,a4.w};
            float b[4] = {b4.x,b4.y,b4.z,b4.w};
#pragma unroll
            for (int i = 0; i < 4; ++i)
#pragma unroll
                for (int j = 0; j < 4; ++j) acc[i][j] += a[i]*b[j];
        }
        __syncthreads();
    }
#pragma unroll
    for (int i = 0; i < 4; ++i) {
        int r = row0 + (ty<<2) + i;
        if (r < M)
            *(float4*)(C + (size_t)r * N + col0 + (tx<<2)) =
                make_float4(acc[i][0],acc[i][1],acc[i][2],acc[i][3]);
    }
}

// ------------- per-node attention logits ------------------------------------
__global__ void logits_k(const float* __restrict__ h,
                         const float* __restrict__ a_s,
                         const float* __restrict__ a_d,
                         float* __restrict__ als, float* __restrict__ ald,
                         int H, int C)
{
    int n = blockIdx.x;
    int head = threadIdx.x >> 6;
    int lane = threadIdx.x & 63;
    const float* row = h + (size_t)n * H * C + head * C;
    float ss = 0.f, sd = 0.f;
    for (int c = lane; c < C; c += 64) {
        float v = row[c];
        ss += v * a_s[head*C + c];
        sd += v * a_d[head*C + c];
    }
    for (int o = 32; o > 0; o >>= 1) { ss += __shfl_down(ss,o); sd += __shfl_down(sd,o); }
    if (lane == 0) { als[(size_t)n*H + head] = ss; ald[(size_t)n*H + head] = sd; }
}

// ---------------- CSR build -------------------------------------------------
__global__ void zero_k(int* p, int n) {
    int i = blockIdx.x*blockDim.x + threadIdx.x; if (i < n) p[i] = 0;
}
__global__ void count_k(const int* __restrict__ ei, int* __restrict__ cnt) {
    int i = blockIdx.x*blockDim.x + threadIdx.x;
    if (i >= TOT_E) return;
    int d = (i < N_EDGES) ? ei[N_EDGES + i] : (i - N_EDGES);
    atomicAdd(&cnt[d], 1);
}
__global__ __launch_bounds__(1024) void scan_k(const int* __restrict__ cnt,
                                               int* __restrict__ offs,
                                               int* __restrict__ cursor)
{
    __shared__ int sm[1024];
    __shared__ int carry_s;
    if (threadIdx.x == 0) carry_s = 0;
    __syncthreads();
    for (int base = 0; base < N_NODES; base += 1024) {
        int i = base + threadIdx.x;
        int v = (i < N_NODES) ? cnt[i] : 0;
        sm[threadIdx.x] = v;
        __syncthreads();
        for (int off = 1; off < 1024; off <<= 1) {
            int t = (threadIdx.x >= off) ? sm[threadIdx.x - off] : 0;
            __syncthreads();
            sm[threadIdx.x] += t;
            __syncthreads();
        }
        int c = carry_s;
        if (i < N_NODES) {
            offs[i+1]  = c + sm[threadIdx.x];
            cursor[i]  = c + sm[threadIdx.x] - v;
        }
        __syncthreads();
        if (threadIdx.x == 1023) carry_s = c + sm[1023];
        __syncthreads();
    }
    if (threadIdx.x == 0) offs[0] = 0;
}
__global__ void scatter_k(const int* __restrict__ ei, int* __restrict__ cursor,
                          int* __restrict__ ssrc)
{
    int i = blockIdx.x*blockDim.x + threadIdx.x;
    if (i >= TOT_E) return;
    int s, d;
    if (i < N_EDGES) { s = ei[i]; d = ei[N_EDGES + i]; }
    else             { s = i - N_EDGES; d = s; }
    int pos = atomicAdd(&cursor[d], 1);
    ssrc[pos] = s;
}

// ---------------- per-dst softmax + weighted aggregation --------------------
// one block per dst node; T = H*C/4 threads, each owns 4 contiguous channels
// DUAL: out dtype selected at runtime via *flag (1=bf16, 0=fp32)
template<int H, int C, bool PRELU, bool DUAL>
__global__ void aggregate_k(const float* __restrict__ h,
                            const float* __restrict__ als,
                            const float* __restrict__ ald,
                            const int* __restrict__ offs,
                            const int* __restrict__ ssrc,
                            const float* __restrict__ bias,
                            const float* __restrict__ prelu_w,
                            void* __restrict__ outv,
                            const int* __restrict__ flag)
{
    constexpr int CT = H * C;
    constexpr int T  = CT / 4;
    int n   = blockIdx.x;
    int tid = threadIdx.x;
    int beg = offs[n], end = offs[n+1];

    __shared__ float s_ald[H], s_m[H], s_den[H];
    __shared__ float rbuf[H][T];
    if (tid < H) s_ald[tid] = ald[(size_t)n*H + tid];
    __syncthreads();

    // pass 1: per-head max of leaky logits
    float lmax[H];
#pragma unroll
    for (int hh = 0; hh < H; ++hh) lmax[hh] = -FLT_MAX;
    for (int e = beg + tid; e < end; e += T) {
        int s = ssrc[e];
#pragma unroll
        for (int hh = 0; hh < H; ++hh) {
            float l = als[(size_t)s*H + hh] + s_ald[hh];
            l = (l >= 0.f) ? l : 0.2f*l;
            lmax[hh] = fmaxf(lmax[hh], l);
        }
    }
#pragma unroll
    for (int hh = 0; hh < H; ++hh) rbuf[hh][tid] = lmax[hh];
    __syncthreads();
    for (int srd = T/2; srd > 0; srd >>= 1) {
        if (tid < srd)
#pragma unroll
            for (int hh = 0; hh < H; ++hh)
                rbuf[hh][tid] = fmaxf(rbuf[hh][tid], rbuf[hh][tid+srd]);
        __syncthreads();
    }
    if (tid < H) s_m[tid] = rbuf[tid][0];
    __syncthreads();

    // pass 2: per-head sum of exp(l - m)
    float lsum[H];
#pragma unroll
    for (int hh = 0; hh < H; ++hh) lsum[hh] = 0.f;
    for (int e = beg + tid; e < end; e += T) {
        int s = ssrc[e];
#pragma unroll
        for (int hh = 0; hh < H; ++hh) {
            float l = als[(size_t)s*H + hh] + s_ald[hh];
            l = (l >= 0.f) ? l : 0.2f*l;
            lsum[hh] += __expf(l - s_m[hh]);
        }
    }
#pragma unroll
    for (int hh = 0; hh < H; ++hh) rbuf[hh][tid] = lsum[hh];
    __syncthreads();
    for (int srd = T/2; srd > 0; srd >>= 1) {
        if (tid < srd)
#pragma unroll
            for (int hh = 0; hh < H; ++hh)
                rbuf[hh][tid] += rbuf[hh][tid+srd];
        __syncthreads();
    }
    if (tid < H) s_den[tid] = rbuf[tid][0];
    __syncthreads();

    // pass 3: weighted accumulation of h[src] rows
    const int hh = (4*tid) / C;
    float m = s_m[hh], inv_den = 1.0f / s_den[hh], aldh = s_ald[hh];
    float ax=0.f, ay=0.f, az=0.f, aw=0.f;
    for (int e = beg; e < end; ++e) {
        int s = ssrc[e];
        float l = als[(size_t)s*H + hh] + aldh;
        l = (l >= 0.f) ? l : 0.2f*l;
        float w = __expf(l - m) * inv_den;
        float4 v = *(const float4*)(h + (size_t)s*CT + 4*tid);
        ax += w*v.x; ay += w*v.y; az += w*v.z; aw += w*v.w;
    }
    float bb[4];
    load4(bias + 4*tid, bb);
    ax += bb[0]; ay += bb[1]; az += bb[2]; aw += bb[3];
    if (PRELU) {
        float pw = *prelu_w;
        ax = ax >= 0.f ? ax : pw*ax;
        ay = ay >= 0.f ? ay : pw*ay;
        az = az >= 0.f ? az : pw*az;
        aw = aw >= 0.f ? aw : pw*aw;
    }
    size_t ofs = (size_t)n*CT + 4*tid;
    if (DUAL) {
        if (*flag) store4b((u16*)outv + ofs, ax, ay, az, aw);
        else       store4f((float*)outv + ofs, ax, ay, az, aw);
    } else {
        store4f((float*)outv + ofs, ax, ay, az, aw);
    }
}

// ---------------------------------------------------------------------------
extern "C" void kernel_launch(void* const* d_in, const int* in_sizes, int n_in,
                              void* d_out, int out_size, void* d_ws, size_t ws_size,
                              hipStream_t stream)
{
    const void* x   = d_in[0];
    const int*  ei  = (const int*)d_in[1];
    const void* W1  = d_in[2];
    const void* as1 = d_in[3];
    const void* ad1 = d_in[4];
    const void* b1  = d_in[5];
    const void* pw  = d_in[6];
    const void* W2  = d_in[7];
    const void* as2 = d_in[8];
    const void* ad2 = d_in[9];
    const void* b2  = d_in[10];

    float* ws = (float*)d_ws;
    int*   flag = (int*)ws;                               // +4 pad
    float* xf   = ws + 4;                                 // 7,680,000
    float* W1f  = xf  + (size_t)N_NODES*IN_CH;            // 131,072
    float* W2f  = W1f + IN_CH*HEADS*HID;                  // 131,072
    float* as1f = W2f + HEADS*HID*OUT_CH;                 // 512
    float* ad1f = as1f + HEADS*HID;                       // 512
    float* b1f  = ad1f + HEADS*HID;                       // 512
    float* as2f = b1f  + HEADS*HID;                       // 256
    float* ad2f = as2f + OUT_CH;                          // 256
    float* b2f  = ad2f + OUT_CH;                          // 256
    float* pwf  = b2f  + OUT_CH;                          // 4 (pad)
    float* h1   = pwf + 4;                                // 15,360,000
    float* h1p  = h1  + (size_t)N_NODES*512;              // 15,360,000
    float* als1 = h1p + (size_t)N_NODES*512;              // 120,000
    float* ald1 = als1 + (size_t)N_NODES*4;               // 120,000
    float* als2v = ald1 + (size_t)N_NODES*4;              // 30,000
    float* ald2v = als2v + N_NODES;                       // 30,000
    int*   cnt    = (int*)(ald2v + N_NODES);              // 30,000
    int*   offs   = cnt + N_NODES;                        // 30,001
    int*   cursor = offs + (N_NODES+1);                   // 30,000
    int*   ssrc   = cursor + N_NODES;                     // 510,000
    float* h2 = h1;  // h1 dead after aggregate1; reuse for h2 (30000*256)

    // dtype detect + materialize fp32 inputs
    detect_k<<<1, 256, 0, stream>>>((const unsigned int*)x, flag);
    convert_k<<<(N_NODES*IN_CH+255)/256, 256, 0, stream>>>(x,  xf,  N_NODES*IN_CH, flag);
    convert_k<<<(IN_CH*HEADS*HID+255)/256, 256, 0, stream>>>(W1, W1f, IN_CH*HEADS*HID, flag);
    convert_k<<<(HEADS*HID*OUT_CH+255)/256, 256, 0, stream>>>(W2, W2f, HEADS*HID*OUT_CH, flag);
    convert_k<<<2, 256, 0, stream>>>(as1, as1f, HEADS*HID, flag);
    convert_k<<<2, 256, 0, stream>>>(ad1, ad1f, HEADS*HID, flag);
    convert_k<<<2, 256, 0, stream>>>(b1,  b1f,  HEADS*HID, flag);
    convert_k<<<1, 256, 0, stream>>>(as2, as2f, OUT_CH, flag);
    convert_k<<<1, 256, 0, stream>>>(ad2, ad2f, OUT_CH, flag);
    convert_k<<<1, 256, 0, stream>>>(b2,  b2f,  OUT_CH, flag);
    convert_k<<<1, 64,  0, stream>>>(pw,  pwf,  1, flag);

    // CSR build
    zero_k   <<<(N_NODES+255)/256, 256, 0, stream>>>(cnt, N_NODES);
    count_k  <<<(TOT_E+255)/256,   256, 0, stream>>>(ei, cnt);
    scan_k   <<<1, 1024, 0, stream>>>(cnt, offs, cursor);
    scatter_k<<<(TOT_E+255)/256,   256, 0, stream>>>(ei, cursor, ssrc);

    // ---- layer 1 ----
    dim3 g1(512/64, (N_NODES+63)/64);
    gemm_k<<<g1, 256, 0, stream>>>(xf, W1f, h1, N_NODES, 512, IN_CH);
    logits_k<<<N_NODES, 256, 0, stream>>>(h1, as1f, ad1f, als1, ald1, HEADS, HID);
    aggregate_k<HEADS, HID, true, false>
        <<<N_NODES, (HEADS*HID)/4, 0, stream>>>(h1, als1, ald1, offs, ssrc, b1f, pwf, h1p, flag);

    // ---- layer 2 ----
    dim3 g2(256/64, (N_NODES+63)/64);
    gemm_k<<<g2, 256, 0, stream>>>(h1p, W2f, h2, N_NODES, OUT_CH, 512);
    logits_k<<<N_NODES, 64, 0, stream>>>(h2, as2f, ad2f, als2v, ald2v, 1, OUT_CH);
    aggregate_k<1, OUT_CH, false, true>
        <<<N_NODES, OUT_CH/4, 0, stream>>>(h2, als2v, ald2v, offs, ssrc, b2f, nullptr, d_out, flag);
}